// Round 5
// baseline (2102.586 us; speedup 1.0000x reference)
//
#include <hip/hip_runtime.h>

// Problem constants
#define PAD_ID 0
#define NTOK   16384          // B*L = 16*1024
#define DIM    768
#define KLAT   5000
#define KPAD   5024           // 157*32, zero-padded latent rows
#define NSTEP  157            // 5024/32
#define TILE_SH 24576         // shorts per 32x768 tile (48 KB)
#define TOKB   64             // tokens per block (256 blocks, 512 threads)

typedef float f32x4 __attribute__((ext_vector_type(4)));
typedef __bf16 bf16x8 __attribute__((ext_vector_type(8)));

__device__ __forceinline__ unsigned int f2bf(float f) {
    unsigned int u = __float_as_uint(f);
    u += 0x7fffu + ((u >> 16) & 1u);   // RNE
    return u >> 16;
}
__device__ __forceinline__ float bf2f(unsigned short h) {
    return __uint_as_float(((unsigned int)h) << 16);
}
__device__ __forceinline__ void async_cp16(const unsigned short* g, unsigned short* l) {
    __builtin_amdgcn_global_load_lds(
        (const __attribute__((address_space(1))) unsigned int*)g,
        (__attribute__((address_space(3))) unsigned int*)l, 16, 0, 0);
}

// ---------------------------------------------------------------------------
// Kernel 0a: latent -> latbS, bf16, MFMA-A-fragment order per 32-row tile.
// ---------------------------------------------------------------------------
__global__ __launch_bounds__(256) void cvt_latS(const float* __restrict__ latent,
                                                unsigned short* __restrict__ latbS) {
    int g = blockIdx.x * 256 + threadIdx.x;
    if (g >= NSTEP * 24 * 2 * 64) return;
    int lane = g & 63; int rest = g >> 6;
    int h = rest & 1;  int kfr = rest >> 1;
    int kf = kfr % 24; int t  = kfr / 24;
    int row = t * 32 + h * 16 + (lane & 15);
    int col = kf * 32 + (lane >> 4) * 8;
    float4 v0 = make_float4(0.f,0.f,0.f,0.f), v1 = v0;
    if (row < KLAT) {
        v0 = *(const float4*)(latent + (long)row * DIM + col);
        v1 = *(const float4*)(latent + (long)row * DIM + col + 4);
    }
    uint4 o;
    o.x = f2bf(v0.x) | (f2bf(v0.y) << 16);
    o.y = f2bf(v0.z) | (f2bf(v0.w) << 16);
    o.z = f2bf(v1.x) | (f2bf(v1.y) << 16);
    o.w = f2bf(v1.z) | (f2bf(v1.w) << 16);
    *(uint4*)(latbS + (size_t)g * 8) = o;
}

// ---------------------------------------------------------------------------
// Kernel 0b: latent -> latbT, bf16, d-major per tile.
// ---------------------------------------------------------------------------
__global__ __launch_bounds__(256) void cvt_latT(const float* __restrict__ latent,
                                                unsigned short* __restrict__ latbT) {
    int g = blockIdx.x * 256 + threadIdx.x;
    if (g >= NSTEP * DIM * 4) return;
    int kk8 = g & 3; int rest = g >> 2;
    int d = rest % DIM; int t = rest / DIM;
    int kk0 = kk8 * 8;
    unsigned short v[8];
    #pragma unroll
    for (int j = 0; j < 8; ++j) {
        int row = t * 32 + kk0 + j;
        v[j] = (row < KLAT) ? (unsigned short)f2bf(latent[(long)row * DIM + d])
                            : (unsigned short)0;
    }
    *(uint4*)(latbT + (size_t)g * 8) = *(uint4*)v;
}

// ---------------------------------------------------------------------------
// Kernel 1: lang_emb = tanh(masked-mean of char embeddings), stored bf16.
// ---------------------------------------------------------------------------
__global__ __launch_bounds__(192) void build_lang(const int* __restrict__ x,
                                                  const float* __restrict__ cemb,
                                                  unsigned short* __restrict__ langb) {
    int tok = blockIdx.x;
    int t = threadIdx.x;
    const int* xs = x + tok * 8;
    int ids[8]; int cnt = 0;
    #pragma unroll
    for (int c = 0; c < 8; ++c) { ids[c] = xs[c]; cnt += (ids[c] != PAD_ID); }
    float4 acc = make_float4(0.f, 0.f, 0.f, 0.f);
    #pragma unroll
    for (int c = 0; c < 8; ++c) {
        if (ids[c] != PAD_ID) {
            float4 v = *(const float4*)(cemb + (long)ids[c] * DIM + t * 4);
            acc.x += v.x; acc.y += v.y; acc.z += v.z; acc.w += v.w;
        }
    }
    float cntf = (float)max(cnt, 1);
    unsigned int u0 = f2bf(tanhf(acc.x / cntf)) | (f2bf(tanhf(acc.y / cntf)) << 16);
    unsigned int u1 = f2bf(tanhf(acc.z / cntf)) | (f2bf(tanhf(acc.w / cntf)) << 16);
    *(uint2*)(langb + tok * DIM + t * 4) = make_uint2(u0, u1);
}

// ---------------------------------------------------------------------------
// Kernel 2: v4 (proven, 424us) — unchanged, produces the real output.
// ---------------------------------------------------------------------------
__global__ __launch_bounds__(512, 2) void fused_sde(
        const int* __restrict__ x, const float* __restrict__ cemb,
        const unsigned short* __restrict__ langb,
        const unsigned short* __restrict__ latbS,
        const unsigned short* __restrict__ latbT,
        float* __restrict__ out) {
    __shared__ unsigned short sLat[2][TILE_SH];
    __shared__ unsigned short sP[2][TOKB * 40];
    __shared__ float sL[2][TOKB];

    const int tid  = threadIdx.x;
    const int w    = tid >> 6;
    const int lane = tid & 63;
    const int lr   = lane & 15;
    const int q    = lane >> 4;
    const int tt   = w & 3;
    const int lt   = w >> 2;
    const int m0   = blockIdx.x * TOKB;

    uint4 qf[24];
    {
        const unsigned short* qr = langb + (m0 + tt * 16 + lr) * DIM;
        #pragma unroll
        for (int kf = 0; kf < 24; ++kf)
            qf[kf] = *(const uint4*)(qr + kf * 32 + q * 8);
    }

    f32x4 accO[4][6];
    #pragma unroll
    for (int mt = 0; mt < 4; ++mt)
        #pragma unroll
        for (int dt = 0; dt < 6; ++dt)
            accO[mt][dt] = (f32x4){0.f, 0.f, 0.f, 0.f};
    float lpart = 0.f;

    const int aBase = lt * 64 + lane;
    const int bBase = (w * 96 + lr) * 32 + q * 8;

    #pragma unroll
    for (int i = 0; i < 6; ++i)
        async_cp16(latbS + ((size_t)i * 512 + tid) * 8,
                   &sLat[0][(i * 512 + (tid & ~63)) * 8]);
    __syncthreads();

    for (int s = 0; s < NSTEP; ++s) {
        const int c = s & 1;
        {
            int nt = (s + 1 < NSTEP) ? s + 1 : 0;
            const unsigned short* gs = latbS + (size_t)nt * TILE_SH;
            #pragma unroll
            for (int i = 0; i < 6; ++i)
                async_cp16(gs + ((size_t)i * 512 + tid) * 8,
                           &sLat[c ^ 1][(i * 512 + (tid & ~63)) * 8]);
        }
        const unsigned short* bt = latbT + (size_t)s * TILE_SH;
        uint4 bO0[3], bO1[3];
        #pragma unroll
        for (int dt = 0; dt < 3; ++dt)
            bO0[dt] = *(const uint4*)(bt + bBase + dt * 512);

        f32x4 sva = {0.f,0.f,0.f,0.f}, svb = {0.f,0.f,0.f,0.f};
        #pragma unroll
        for (int kp = 0; kp < 12; ++kp) {
            bf16x8 a0 = *(const bf16x8*)&sLat[c][((2 * kp)     * 128 + aBase) * 8];
            bf16x8 a1 = *(const bf16x8*)&sLat[c][((2 * kp + 1) * 128 + aBase) * 8];
            bf16x8 b0 = *(const bf16x8*)&qf[2 * kp];
            bf16x8 b1 = *(const bf16x8*)&qf[2 * kp + 1];
            sva = __builtin_amdgcn_mfma_f32_16x16x32_bf16(a0, b0, sva, 0, 0, 0);
            svb = __builtin_amdgcn_mfma_f32_16x16x32_bf16(a1, b1, svb, 0, 0, 0);
        }

        #pragma unroll
        for (int dt = 0; dt < 3; ++dt)
            bO1[dt] = *(const uint4*)(bt + bBase + (dt + 3) * 512);

        {
            const int lat0 = s * 32 + lt * 16 + q * 4;
            f32x4 sv = sva + svb;
            float e0 = (lat0     < KLAT) ? __expf(sv[0]) : 0.f;
            float e1 = (lat0 + 1 < KLAT) ? __expf(sv[1]) : 0.f;
            float e2 = (lat0 + 2 < KLAT) ? __expf(sv[2]) : 0.f;
            float e3 = (lat0 + 3 < KLAT) ? __expf(sv[3]) : 0.f;
            lpart += (e0 + e1) + (e2 + e3);
            unsigned int p01 = f2bf(e0) | (f2bf(e1) << 16);
            unsigned int p23 = f2bf(e2) | (f2bf(e3) << 16);
            *(uint2*)&sP[c][(tt * 16 + lr) * 40 + lt * 16 + q * 4] =
                make_uint2(p01, p23);
        }

        __syncthreads();

        bf16x8 pA[4];
        #pragma unroll
        for (int mt = 0; mt < 4; ++mt)
            pA[mt] = *(const bf16x8*)&sP[c][(mt * 16 + lr) * 40 + q * 8];
        #pragma unroll
        for (int dt = 0; dt < 3; ++dt) {
            bf16x8 b = *(const bf16x8*)&bO0[dt];
            #pragma unroll
            for (int mt = 0; mt < 4; ++mt)
                accO[mt][dt] = __builtin_amdgcn_mfma_f32_16x16x32_bf16(
                    pA[mt], b, accO[mt][dt], 0, 0, 0);
        }
        #pragma unroll
        for (int dt = 0; dt < 3; ++dt) {
            bf16x8 b = *(const bf16x8*)&bO1[dt];
            #pragma unroll
            for (int mt = 0; mt < 4; ++mt)
                accO[mt][dt + 3] = __builtin_amdgcn_mfma_f32_16x16x32_bf16(
                    pA[mt], b, accO[mt][dt + 3], 0, 0, 0);
        }
    }

    lpart += __shfl_xor(lpart, 16, 64);
    lpart += __shfl_xor(lpart, 32, 64);
    if (lane < 16) sL[lt][tt * 16 + lane] = lpart;
    __syncthreads();

    #pragma unroll
    for (int mt = 0; mt < 4; ++mt) {
        int tl0 = mt * 16 + q * 4;
        float linv[4]; int fid[4];
        #pragma unroll
        for (int r = 0; r < 4; ++r) {
            linv[r] = 1.0f / (sL[0][tl0 + r] + sL[1][tl0 + r]);
            fid[r]  = x[(m0 + tl0 + r) * 8];
        }
        #pragma unroll
        for (int dt = 0; dt < 6; ++dt) {
            int d = w * 96 + dt * 16 + lr;
            #pragma unroll
            for (int r = 0; r < 4; ++r) {
                int tok = m0 + tl0 + r;
                float v = accO[mt][dt][r] * linv[r] + bf2f(langb[tok * DIM + d]);
                if (fid[r] < 4) v = cemb[fid[r] * DIM + d];
                out[tok * DIM + d] = v;
            }
        }
    }
}

// ---------------------------------------------------------------------------
// ABLATION PROBES: v4 clone, one phase deleted each, junk -> scratch.
//   V0 full | V1 no A-frag ds_reads | V2 no S (MFMA+reads) | V3 no O (MFMA+pA+bO)
//   V4 no global streams (DMA+bO) | V5 barrier only every 16 steps
// DCE guards: deleted-phase consumers kept live (exp chain / qsum sink / acc sum).
// Outputs are intentionally garbage; written to workspace scratch only.
// ---------------------------------------------------------------------------
template<int ABL>
__global__ __launch_bounds__(512, 2) void fused_abl(
        const unsigned short* __restrict__ langb,
        const unsigned short* __restrict__ latbS,
        const unsigned short* __restrict__ latbT,
        uint4* __restrict__ scr) {
    __shared__ unsigned short sLat[2][TILE_SH];
    __shared__ unsigned short sP[2][TOKB * 40];

    const int tid  = threadIdx.x;
    const int w    = tid >> 6;
    const int lane = tid & 63;
    const int lr   = lane & 15;
    const int q    = lane >> 4;
    const int tt   = w & 3;
    const int lt   = w >> 2;
    const int m0   = blockIdx.x * TOKB;

    uint4 qf[24];
    {
        const unsigned short* qr = langb + (m0 + tt * 16 + lr) * DIM;
        #pragma unroll
        for (int kf = 0; kf < 24; ++kf)
            qf[kf] = *(const uint4*)(qr + kf * 32 + q * 8);
    }

    f32x4 accO[4][6];
    #pragma unroll
    for (int mt = 0; mt < 4; ++mt)
        #pragma unroll
        for (int dt = 0; dt < 6; ++dt)
            accO[mt][dt] = (f32x4){0.f, 0.f, 0.f, 0.f};
    float lpart = 0.f;

    // V2: keep qf loads live without S-MFMA
    float qsum = 0.f;
    if constexpr (ABL == 2) {
        #pragma unroll
        for (int kf = 0; kf < 24; ++kf) qsum += (float)(qf[kf].x & 1u);
        qsum *= 1e-30f;
    }

    const int aBase = lt * 64 + lane;
    const int bBase = (w * 96 + lr) * 32 + q * 8;

    if constexpr (ABL != 4) {
        #pragma unroll
        for (int i = 0; i < 6; ++i)
            async_cp16(latbS + ((size_t)i * 512 + tid) * 8,
                       &sLat[0][(i * 512 + (tid & ~63)) * 8]);
    }
    __syncthreads();

    // V1: preload constant A-frags once (real data from tile 0)
    bf16x8 a0c, a1c;
    if constexpr (ABL == 1) {
        a0c = *(const bf16x8*)&sLat[0][(aBase) * 8];
        a1c = *(const bf16x8*)&sLat[0][(128 + aBase) * 8];
    }

    const uint4 bOc = make_uint4(0x3f803f80u, 0x3f803f80u, 0x3f803f80u, 0x3f803f80u);

    for (int s = 0; s < NSTEP; ++s) {
        const int c = s & 1;
        if constexpr (ABL != 4) {
            int nt = (s + 1 < NSTEP) ? s + 1 : 0;
            const unsigned short* gs = latbS + (size_t)nt * TILE_SH;
            #pragma unroll
            for (int i = 0; i < 6; ++i)
                async_cp16(gs + ((size_t)i * 512 + tid) * 8,
                           &sLat[c ^ 1][(i * 512 + (tid & ~63)) * 8]);
        }
        const unsigned short* bt = latbT + (size_t)s * TILE_SH;
        uint4 bO0[3], bO1[3];
        if constexpr (ABL != 3 && ABL != 4) {
            #pragma unroll
            for (int dt = 0; dt < 3; ++dt)
                bO0[dt] = *(const uint4*)(bt + bBase + dt * 512);
        } else {
            #pragma unroll
            for (int dt = 0; dt < 3; ++dt) bO0[dt] = bOc;
        }

        f32x4 sva = {0.f,0.f,0.f,0.f}, svb = {0.f,0.f,0.f,0.f};
        if constexpr (ABL == 2) {
            sva[0] = qsum; svb[0] = qsum;
        } else {
            #pragma unroll
            for (int kp = 0; kp < 12; ++kp) {
                bf16x8 a0, a1;
                if constexpr (ABL == 1) { a0 = a0c; a1 = a1c; }
                else {
                    a0 = *(const bf16x8*)&sLat[c][((2 * kp)     * 128 + aBase) * 8];
                    a1 = *(const bf16x8*)&sLat[c][((2 * kp + 1) * 128 + aBase) * 8];
                }
                bf16x8 b0 = *(const bf16x8*)&qf[2 * kp];
                bf16x8 b1 = *(const bf16x8*)&qf[2 * kp + 1];
                sva = __builtin_amdgcn_mfma_f32_16x16x32_bf16(a0, b0, sva, 0, 0, 0);
                svb = __builtin_amdgcn_mfma_f32_16x16x32_bf16(a1, b1, svb, 0, 0, 0);
            }
        }

        if constexpr (ABL != 3 && ABL != 4) {
            #pragma unroll
            for (int dt = 0; dt < 3; ++dt)
                bO1[dt] = *(const uint4*)(bt + bBase + (dt + 3) * 512);
        } else {
            #pragma unroll
            for (int dt = 0; dt < 3; ++dt) bO1[dt] = bOc;
        }

        {
            const int lat0 = s * 32 + lt * 16 + q * 4;
            f32x4 sv = sva + svb;
            float e0 = (lat0     < KLAT) ? __expf(sv[0]) : 0.f;
            float e1 = (lat0 + 1 < KLAT) ? __expf(sv[1]) : 0.f;
            float e2 = (lat0 + 2 < KLAT) ? __expf(sv[2]) : 0.f;
            float e3 = (lat0 + 3 < KLAT) ? __expf(sv[3]) : 0.f;
            lpart += (e0 + e1) + (e2 + e3);
            unsigned int p01 = f2bf(e0) | (f2bf(e1) << 16);
            unsigned int p23 = f2bf(e2) | (f2bf(e3) << 16);
            *(uint2*)&sP[c][(tt * 16 + lr) * 40 + lt * 16 + q * 4] =
                make_uint2(p01, p23);
        }

        if constexpr (ABL == 5) {
            if ((s & 15) == 15) __syncthreads();
        } else {
            __syncthreads();
        }

        if constexpr (ABL != 3) {
            bf16x8 pA[4];
            #pragma unroll
            for (int mt = 0; mt < 4; ++mt)
                pA[mt] = *(const bf16x8*)&sP[c][(mt * 16 + lr) * 40 + q * 8];
            #pragma unroll
            for (int dt = 0; dt < 3; ++dt) {
                bf16x8 b = *(const bf16x8*)&bO0[dt];
                #pragma unroll
                for (int mt = 0; mt < 4; ++mt)
                    accO[mt][dt] = __builtin_amdgcn_mfma_f32_16x16x32_bf16(
                        pA[mt], b, accO[mt][dt], 0, 0, 0);
            }
            #pragma unroll
            for (int dt = 0; dt < 3; ++dt) {
                bf16x8 b = *(const bf16x8*)&bO1[dt];
                #pragma unroll
                for (int mt = 0; mt < 4; ++mt)
                    accO[mt][dt + 3] = __builtin_amdgcn_mfma_f32_16x16x32_bf16(
                        pA[mt], b, accO[mt][dt + 3], 0, 0, 0);
            }
        }
    }

    // keep everything live; junk out to scratch
    float acc = lpart;
    if constexpr (ABL != 3) {
        #pragma unroll
        for (int mt = 0; mt < 4; ++mt)
            #pragma unroll
            for (int dt = 0; dt < 6; ++dt)
                acc += accO[mt][dt][0] + accO[mt][dt][1] +
                       accO[mt][dt][2] + accO[mt][dt][3];
    }
    scr[blockIdx.x * 512 + tid] = make_uint4(__float_as_uint(acc), 0u, 0u, 0u);
}

// ---------------------------------------------------------------------------
extern "C" void kernel_launch(void* const* d_in, const int* in_sizes, int n_in,
                              void* d_out, int out_size, void* d_ws, size_t ws_size,
                              hipStream_t stream) {
    const int*   x      = (const int*)d_in[0];
    const float* cemb   = (const float*)d_in[1];
    const float* latent = (const float*)d_in[2];
    float* out = (float*)d_out;

    unsigned short* langb = (unsigned short*)d_ws;                  // 25.2 MB
    unsigned short* latbS = langb + (size_t)NTOK * DIM;             // 7.7 MB
    unsigned short* latbT = latbS + (size_t)NSTEP * TILE_SH;        // 7.7 MB
    uint4* scr = (uint4*)(latbT + (size_t)NSTEP * TILE_SH);         // 2 MB scratch

    int nS = NSTEP * 24 * 2 * 64;
    int nT = NSTEP * DIM * 4;
    cvt_latS<<<(nS + 255) / 256, 256, 0, stream>>>(latent, latbS);
    cvt_latT<<<(nT + 255) / 256, 256, 0, stream>>>(latent, latbT);
    build_lang<<<NTOK, 192, 0, stream>>>(x, cemb, langb);
    fused_sde<<<NTOK / TOKB, 512, 0, stream>>>(x, cemb, langb, latbS, latbT, out);

    // ---- ablation probes (junk -> scratch; timing/counters via rocprof) ----
    fused_abl<0><<<NTOK / TOKB, 512, 0, stream>>>(langb, latbS, latbT, scr);
    fused_abl<1><<<NTOK / TOKB, 512, 0, stream>>>(langb, latbS, latbT, scr);
    fused_abl<2><<<NTOK / TOKB, 512, 0, stream>>>(langb, latbS, latbT, scr);
    fused_abl<3><<<NTOK / TOKB, 512, 0, stream>>>(langb, latbS, latbT, scr);
    fused_abl<4><<<NTOK / TOKB, 512, 0, stream>>>(langb, latbS, latbT, scr);
    fused_abl<5><<<NTOK / TOKB, 512, 0, stream>>>(langb, latbS, latbT, scr);
}

// Round 6
// 614.160 us; speedup vs baseline: 3.4235x; 3.4235x over previous
//
#include <hip/hip_runtime.h>

// Problem constants
#define PAD_ID 0
#define NTOK   16384          // B*L = 16*1024
#define DIM    768
#define KLAT   5000
#define NSTEP  157            // ceil(5024/32)
#define TILE_SH 24576         // shorts per 32x768 tile (48 KB)
#define TOKB   64             // tokens per block (256 blocks, 512 threads)

typedef float f32x4 __attribute__((ext_vector_type(4)));
typedef __bf16 bf16x8 __attribute__((ext_vector_type(8)));

__device__ __forceinline__ unsigned int f2bf(float f) {
    unsigned int u = __float_as_uint(f);
    u += 0x7fffu + ((u >> 16) & 1u);   // RNE
    return u >> 16;
}
__device__ __forceinline__ float bf2f(unsigned short h) {
    return __uint_as_float(((unsigned int)h) << 16);
}
__device__ __forceinline__ void async_cp16(const unsigned short* g, unsigned short* l) {
    __builtin_amdgcn_global_load_lds(
        (const __attribute__((address_space(1))) unsigned int*)g,
        (__attribute__((address_space(3))) unsigned int*)l, 16, 0, 0);
}
// Explicit barrier usable inside wave-uniform divergent branches.
// Drains this wave's own VMEM (DMA it issued) + LDS ops, then syncs.
__device__ __forceinline__ void gang_bar() {
    asm volatile("s_waitcnt vmcnt(0) lgkmcnt(0)" ::: "memory");
    __builtin_amdgcn_sched_barrier(0);
    __builtin_amdgcn_s_barrier();
    __builtin_amdgcn_sched_barrier(0);
}

// ---------------------------------------------------------------------------
// Kernel 0a: latent -> latbS, bf16, MFMA-A-fragment order per 32-row tile:
//   latbS[t][kf][h][lane][j] = Lat[t*32 + h*16 + (lane&15)][kf*32 + (lane>>4)*8 + j]
// ---------------------------------------------------------------------------
__global__ __launch_bounds__(256) void cvt_latS(const float* __restrict__ latent,
                                                unsigned short* __restrict__ latbS) {
    int g = blockIdx.x * 256 + threadIdx.x;
    if (g >= NSTEP * 24 * 2 * 64) return;
    int lane = g & 63; int rest = g >> 6;
    int h = rest & 1;  int kfr = rest >> 1;
    int kf = kfr % 24; int t  = kfr / 24;
    int row = t * 32 + h * 16 + (lane & 15);
    int col = kf * 32 + (lane >> 4) * 8;
    float4 v0 = make_float4(0.f,0.f,0.f,0.f), v1 = v0;
    if (row < KLAT) {
        v0 = *(const float4*)(latent + (long)row * DIM + col);
        v1 = *(const float4*)(latent + (long)row * DIM + col + 4);
    }
    uint4 o;
    o.x = f2bf(v0.x) | (f2bf(v0.y) << 16);
    o.y = f2bf(v0.z) | (f2bf(v0.w) << 16);
    o.z = f2bf(v1.x) | (f2bf(v1.y) << 16);
    o.w = f2bf(v1.z) | (f2bf(v1.w) << 16);
    *(uint4*)(latbS + (size_t)g * 8) = o;
}

// ---------------------------------------------------------------------------
// Kernel 0b: latent -> latbT, bf16, d-major per tile: latbT[t][d][kk]
// ---------------------------------------------------------------------------
__global__ __launch_bounds__(256) void cvt_latT(const float* __restrict__ latent,
                                                unsigned short* __restrict__ latbT) {
    int g = blockIdx.x * 256 + threadIdx.x;
    if (g >= NSTEP * DIM * 4) return;
    int kk8 = g & 3; int rest = g >> 2;
    int d = rest % DIM; int t = rest / DIM;
    int kk0 = kk8 * 8;
    unsigned short v[8];
    #pragma unroll
    for (int j = 0; j < 8; ++j) {
        int row = t * 32 + kk0 + j;
        v[j] = (row < KLAT) ? (unsigned short)f2bf(latent[(long)row * DIM + d])
                            : (unsigned short)0;
    }
    *(uint4*)(latbT + (size_t)g * 8) = *(uint4*)v;
}

// ---------------------------------------------------------------------------
// Kernel 1: lang_emb = tanh(masked-mean of char embeddings), stored bf16.
// ---------------------------------------------------------------------------
__global__ __launch_bounds__(192) void build_lang(const int* __restrict__ x,
                                                  const float* __restrict__ cemb,
                                                  unsigned short* __restrict__ langb) {
    int tok = blockIdx.x;
    int t = threadIdx.x;
    const int* xs = x + tok * 8;
    int ids[8]; int cnt = 0;
    #pragma unroll
    for (int c = 0; c < 8; ++c) { ids[c] = xs[c]; cnt += (ids[c] != PAD_ID); }
    float4 acc = make_float4(0.f, 0.f, 0.f, 0.f);
    #pragma unroll
    for (int c = 0; c < 8; ++c) {
        if (ids[c] != PAD_ID) {
            float4 v = *(const float4*)(cemb + (long)ids[c] * DIM + t * 4);
            acc.x += v.x; acc.y += v.y; acc.z += v.z; acc.w += v.w;
        }
    }
    float cntf = (float)max(cnt, 1);
    unsigned int u0 = f2bf(tanhf(acc.x / cntf)) | (f2bf(tanhf(acc.y / cntf)) << 16);
    unsigned int u1 = f2bf(tanhf(acc.z / cntf)) | (f2bf(tanhf(acc.w / cntf)) << 16);
    *(uint2*)(langb + tok * DIM + t * 4) = make_uint2(u0, u1);
}

// ---------------------------------------------------------------------------
// Kernel 2 (v6): producer/consumer gang split. 512 thr, 256 blocks (1/CU).
// Gang A (waves 0-3): S(p) each period — 48 ds_read_b128 + 48 MFMA + exp ->
//   sP[c]. Gang B (waves 4-7): DMA(p+1) issue + O(p-1) (bO stream + 48 MFMA
//   into accO[4][12]) + final epilogue. ONE barrier per period; both loops
//   execute exactly 158 barriers (A: 157 + sL-publish; B: 158).
// Resources now overlap across gangs: DS-pipe (A) || MFMA (A+B) || L2 streams
// (B) || VALU exp (A) instead of serializing in lockstep phases.
// Hazards: DMA(p+1)->sLat[c^1] issued period p, read by A at p+1 (B's
// gang_bar drains its own vmcnt before the barrier); sP[c] written at p,
// read at p+1, rewritten at p+2.
// ---------------------------------------------------------------------------
__global__ __launch_bounds__(512, 2) void fused_sde(
        const int* __restrict__ x, const float* __restrict__ cemb,
        const unsigned short* __restrict__ langb,
        const unsigned short* __restrict__ latbS,
        const unsigned short* __restrict__ latbT,
        float* __restrict__ out) {
    __shared__ unsigned short sLat[2][TILE_SH];   // 96 KB
    __shared__ unsigned short sP[2][TOKB * 40];   // 10 KB, row pitch 40 (+8 pad)
    __shared__ float sL[TOKB];

    const int tid  = threadIdx.x;
    const int w    = tid >> 6;
    const int lane = tid & 63;
    const int lr   = lane & 15;
    const int q    = lane >> 4;
    const int m0   = blockIdx.x * TOKB;

    // Prologue: DMA tile 0 -> buf 0 (all 512 threads), then uniform barrier.
    #pragma unroll
    for (int i = 0; i < 6; ++i)
        async_cp16(latbS + ((size_t)i * 512 + tid) * 8,
                   &sLat[0][(i * 512 + (tid & ~63)) * 8]);
    __syncthreads();

    if (w < 4) {
        // ================= GANG A: S-phase producer =================
        const int tt = w;                      // token tile (16 toks)
        uint4 qf[24];
        {
            const unsigned short* qr = langb + (m0 + tt * 16 + lr) * DIM;
            #pragma unroll
            for (int kf = 0; kf < 24; ++kf)
                qf[kf] = *(const uint4*)(qr + kf * 32 + q * 8);
        }
        float lpart = 0.f;

        for (int p = 0; p < NSTEP; ++p) {
            const int c = p & 1;
            f32x4 sva0 = {0.f,0.f,0.f,0.f}, sva1 = {0.f,0.f,0.f,0.f};
            f32x4 svb0 = {0.f,0.f,0.f,0.f}, svb1 = {0.f,0.f,0.f,0.f};
            #pragma unroll
            for (int kp = 0; kp < 12; ++kp) {
                bf16x8 a00 = *(const bf16x8*)&sLat[c][((2*kp)   * 128 +      lane) * 8];
                bf16x8 a01 = *(const bf16x8*)&sLat[c][((2*kp)   * 128 + 64 + lane) * 8];
                bf16x8 a10 = *(const bf16x8*)&sLat[c][((2*kp+1) * 128 +      lane) * 8];
                bf16x8 a11 = *(const bf16x8*)&sLat[c][((2*kp+1) * 128 + 64 + lane) * 8];
                bf16x8 b0 = *(const bf16x8*)&qf[2*kp];
                bf16x8 b1 = *(const bf16x8*)&qf[2*kp+1];
                sva0 = __builtin_amdgcn_mfma_f32_16x16x32_bf16(a00, b0, sva0, 0, 0, 0);
                sva1 = __builtin_amdgcn_mfma_f32_16x16x32_bf16(a01, b0, sva1, 0, 0, 0);
                svb0 = __builtin_amdgcn_mfma_f32_16x16x32_bf16(a10, b1, svb0, 0, 0, 0);
                svb1 = __builtin_amdgcn_mfma_f32_16x16x32_bf16(a11, b1, svb1, 0, 0, 0);
            }
            // exp (no max-sub; |s| = O(1)) and publish P
            {
                const int lat0 = p * 32 + q * 4;      // lt=0 lats; lt=1 at +16
                f32x4 sv0 = sva0 + svb0;
                f32x4 sv1 = sva1 + svb1;
                float e0 = (lat0      < KLAT) ? __expf(sv0[0]) : 0.f;
                float e1 = (lat0 + 1  < KLAT) ? __expf(sv0[1]) : 0.f;
                float e2 = (lat0 + 2  < KLAT) ? __expf(sv0[2]) : 0.f;
                float e3 = (lat0 + 3  < KLAT) ? __expf(sv0[3]) : 0.f;
                float f0 = (lat0 + 16 < KLAT) ? __expf(sv1[0]) : 0.f;
                float f1 = (lat0 + 17 < KLAT) ? __expf(sv1[1]) : 0.f;
                float f2 = (lat0 + 18 < KLAT) ? __expf(sv1[2]) : 0.f;
                float f3 = (lat0 + 19 < KLAT) ? __expf(sv1[3]) : 0.f;
                lpart += (e0 + e1) + (e2 + e3) + (f0 + f1) + (f2 + f3);
                unsigned short* prow = &sP[c][(tt * 16 + lr) * 40];
                *(uint2*)&prow[q * 4] =
                    make_uint2(f2bf(e0) | (f2bf(e1) << 16), f2bf(e2) | (f2bf(e3) << 16));
                *(uint2*)&prow[16 + q * 4] =
                    make_uint2(f2bf(f0) | (f2bf(f1) << 16), f2bf(f2) | (f2bf(f3) << 16));
            }
            gang_bar();                              // bars 1..157
        }
        // softmax denominator (this wave saw ALL lats for its 16 tokens)
        lpart += __shfl_xor(lpart, 16, 64);
        lpart += __shfl_xor(lpart, 32, 64);
        if (lane < 16) sL[tt * 16 + lane] = lpart;
        gang_bar();                                  // bar 158 (publishes sL)
    } else {
        // ================= GANG B: O-phase consumer =================
        const int wb = w - 4;                  // d-slice owner (192 dims)
        const int tb = tid - 256;              // 0..255 within gang
        const int bBase = (wb * 192 + lr) * 32 + q * 8;
        f32x4 accO[4][12];
        #pragma unroll
        for (int mt = 0; mt < 4; ++mt)
            #pragma unroll
            for (int dt = 0; dt < 12; ++dt)
                accO[mt][dt] = (f32x4){0.f, 0.f, 0.f, 0.f};

        for (int p = 0; p <= NSTEP; ++p) {
            const int c = p & 1;
            // DMA next tile (gang B owns the stream; drained at our gang_bar)
            if (p < NSTEP - 1) {
                const unsigned short* gs = latbS + (size_t)(p + 1) * TILE_SH;
                #pragma unroll
                for (int i = 0; i < 12; ++i)
                    async_cp16(gs + ((size_t)(i * 256 + tb)) * 8,
                               &sLat[c ^ 1][(i * 256 + (tb & ~63)) * 8]);
            }
            // O(p-1): P(p-1) from sP[c^1], B-frags streamed from latbT
            if (p > 0) {
                const unsigned short* bt = latbT + (size_t)(p - 1) * TILE_SH;
                bf16x8 pA[4];
                #pragma unroll
                for (int mt = 0; mt < 4; ++mt)
                    pA[mt] = *(const bf16x8*)&sP[c ^ 1][(mt * 16 + lr) * 40 + q * 8];
                #pragma unroll
                for (int r3 = 0; r3 < 3; ++r3) {
                    uint4 bO[4];
                    #pragma unroll
                    for (int j = 0; j < 4; ++j)
                        bO[j] = *(const uint4*)(bt + bBase + (r3 * 4 + j) * 512);
                    #pragma unroll
                    for (int j = 0; j < 4; ++j) {
                        bf16x8 b = *(const bf16x8*)&bO[j];
                        #pragma unroll
                        for (int mt = 0; mt < 4; ++mt)
                            accO[mt][r3 * 4 + j] = __builtin_amdgcn_mfma_f32_16x16x32_bf16(
                                pA[mt], b, accO[mt][r3 * 4 + j], 0, 0, 0);
                    }
                }
            }
            gang_bar();                              // bars 1..158
        }
        // epilogue: /l + lang + special-token override, fp32 out (gang B only)
        #pragma unroll
        for (int mt = 0; mt < 4; ++mt) {
            int tl0 = mt * 16 + q * 4;
            float linv[4]; int fid[4];
            #pragma unroll
            for (int r = 0; r < 4; ++r) {
                linv[r] = 1.0f / sL[tl0 + r];
                fid[r]  = x[(m0 + tl0 + r) * 8];
            }
            #pragma unroll
            for (int dt = 0; dt < 12; ++dt) {
                int d = wb * 192 + dt * 16 + lr;
                #pragma unroll
                for (int r = 0; r < 4; ++r) {
                    int tok = m0 + tl0 + r;
                    float v = accO[mt][dt][r] * linv[r] + bf2f(langb[tok * DIM + d]);
                    if (fid[r] < 4) v = cemb[fid[r] * DIM + d];  // PAD/CLS/SEP/UNK
                    out[tok * DIM + d] = v;
                }
            }
        }
    }
}

// ---------------------------------------------------------------------------
extern "C" void kernel_launch(void* const* d_in, const int* in_sizes, int n_in,
                              void* d_out, int out_size, void* d_ws, size_t ws_size,
                              hipStream_t stream) {
    const int*   x      = (const int*)d_in[0];     // (16,1024,8) int
    const float* cemb   = (const float*)d_in[1];   // (30000,768) f32
    const float* latent = (const float*)d_in[2];   // (5000,768) f32
    float* out = (float*)d_out;                    // (16,1024,768) f32

    unsigned short* langb = (unsigned short*)d_ws;                  // 25.2 MB
    unsigned short* latbS = langb + (size_t)NTOK * DIM;             // 7.7 MB
    unsigned short* latbT = latbS + (size_t)NSTEP * TILE_SH;        // 7.7 MB

    int nS = NSTEP * 24 * 2 * 64;        // frag groups in latbS
    int nT = NSTEP * DIM * 4;            // 8-short groups in latbT
    cvt_latS<<<(nS + 255) / 256, 256, 0, stream>>>(latent, latbS);
    cvt_latT<<<(nT + 255) / 256, 256, 0, stream>>>(latent, latbT);
    build_lang<<<NTOK, 192, 0, stream>>>(x, cemb, langb);
    fused_sde<<<NTOK / TOKB, 512, 0, stream>>>(x, cemb, langb, latbS, latbT, out);
}

// Round 7
// 555.022 us; speedup vs baseline: 3.7883x; 1.1066x over previous
//
#include <hip/hip_runtime.h>

// Problem constants
#define PAD_ID 0
#define NTOK   16384          // B*L = 16*1024
#define DIM    768
#define KLAT   5000
#define NSTEP  157            // ceil(5024/32)
#define TILE_SH 24576         // shorts per 32x768 tile (48 KB)
#define TOKB   64             // tokens per block (256 blocks, 512 threads)

typedef float f32x4 __attribute__((ext_vector_type(4)));
typedef __bf16 bf16x8 __attribute__((ext_vector_type(8)));

__device__ __forceinline__ unsigned int f2bf(float f) {
    unsigned int u = __float_as_uint(f);
    u += 0x7fffu + ((u >> 16) & 1u);   // RNE
    return u >> 16;
}
__device__ __forceinline__ float bf2f(unsigned short h) {
    return __uint_as_float(((unsigned int)h) << 16);
}
__device__ __forceinline__ void async_cp16(const unsigned short* g, unsigned short* l) {
    __builtin_amdgcn_global_load_lds(
        (const __attribute__((address_space(1))) unsigned int*)g,
        (__attribute__((address_space(3))) unsigned int*)l, 16, 0, 0);
}

// ---------------------------------------------------------------------------
// Kernel 0a: latent -> latbS, bf16, MFMA-A-fragment order per 32-row tile:
//   latbS[t][kf][h][lane][j] = Lat[t*32 + h*16 + (lane&15)][kf*32 + (lane>>4)*8 + j]
// ---------------------------------------------------------------------------
__global__ __launch_bounds__(256) void cvt_latS(const float* __restrict__ latent,
                                                unsigned short* __restrict__ latbS) {
    int g = blockIdx.x * 256 + threadIdx.x;
    if (g >= NSTEP * 24 * 2 * 64) return;
    int lane = g & 63; int rest = g >> 6;
    int h = rest & 1;  int kfr = rest >> 1;
    int kf = kfr % 24; int t  = kfr / 24;
    int row = t * 32 + h * 16 + (lane & 15);
    int col = kf * 32 + (lane >> 4) * 8;
    float4 v0 = make_float4(0.f,0.f,0.f,0.f), v1 = v0;
    if (row < KLAT) {
        v0 = *(const float4*)(latent + (long)row * DIM + col);
        v1 = *(const float4*)(latent + (long)row * DIM + col + 4);
    }
    uint4 o;
    o.x = f2bf(v0.x) | (f2bf(v0.y) << 16);
    o.y = f2bf(v0.z) | (f2bf(v0.w) << 16);
    o.z = f2bf(v1.x) | (f2bf(v1.y) << 16);
    o.w = f2bf(v1.z) | (f2bf(v1.w) << 16);
    *(uint4*)(latbS + (size_t)g * 8) = o;
}

// ---------------------------------------------------------------------------
// Kernel 0b: latent -> latbT, bf16, d-major per tile: latbT[t][d][kk]
// ---------------------------------------------------------------------------
__global__ __launch_bounds__(256) void cvt_latT(const float* __restrict__ latent,
                                                unsigned short* __restrict__ latbT) {
    int g = blockIdx.x * 256 + threadIdx.x;
    if (g >= NSTEP * DIM * 4) return;
    int kk8 = g & 3; int rest = g >> 2;
    int d = rest % DIM; int t = rest / DIM;
    int kk0 = kk8 * 8;
    unsigned short v[8];
    #pragma unroll
    for (int j = 0; j < 8; ++j) {
        int row = t * 32 + kk0 + j;
        v[j] = (row < KLAT) ? (unsigned short)f2bf(latent[(long)row * DIM + d])
                            : (unsigned short)0;
    }
    *(uint4*)(latbT + (size_t)g * 8) = *(uint4*)v;
}

// ---------------------------------------------------------------------------
// Kernel 1: lang_emb = tanh(masked-mean of char embeddings), stored bf16.
// ---------------------------------------------------------------------------
__global__ __launch_bounds__(192) void build_lang(const int* __restrict__ x,
                                                  const float* __restrict__ cemb,
                                                  unsigned short* __restrict__ langb) {
    int tok = blockIdx.x;
    int t = threadIdx.x;
    const int* xs = x + tok * 8;
    int ids[8]; int cnt = 0;
    #pragma unroll
    for (int c = 0; c < 8; ++c) { ids[c] = xs[c]; cnt += (ids[c] != PAD_ID); }
    float4 acc = make_float4(0.f, 0.f, 0.f, 0.f);
    #pragma unroll
    for (int c = 0; c < 8; ++c) {
        if (ids[c] != PAD_ID) {
            float4 v = *(const float4*)(cemb + (long)ids[c] * DIM + t * 4);
            acc.x += v.x; acc.y += v.y; acc.z += v.z; acc.w += v.w;
        }
    }
    float cntf = (float)max(cnt, 1);
    unsigned int u0 = f2bf(tanhf(acc.x / cntf)) | (f2bf(tanhf(acc.y / cntf)) << 16);
    unsigned int u1 = f2bf(tanhf(acc.z / cntf)) | (f2bf(tanhf(acc.w / cntf)) << 16);
    *(uint2*)(langb + tok * DIM + t * 4) = make_uint2(u0, u1);
}

// ---------------------------------------------------------------------------
// Kernel 2 (v7): v4 dataflow + T3/T4 counted-vmcnt schedule.
// 3-deep sLat ring; per iter s (steady state):
//   [ bO(s-1) issue | DMA(s+2) issue | S(s): 48 ds_read + 48 MFMA | exp ->
//     sP[s&1] | vmcnt(6) (bO ready, implies DMA(s+1) retired) |
//     O(s-1): 48 pure-reg MFMA, setprio(1) | lgkmcnt(0) | raw s_barrier ]
// vmcnt never drains to 0 in steady state; DMA(s+2) crosses the barrier in
// flight. Hazards: DMA(s+2)->buf[(s+2)%3], last read by S(s-1) which finished
// before iter (s-1)'s barrier; sP[c] written at s, read at s+1 (published by
// iter-s barrier), rewritten at s+2 (after iter s+1 barrier). Tile s+1 is
// complete at iter-s barrier because vmcnt(6) drained DMA(s+1) (older than
// bO(s-1)); barrier gives cross-wave visibility.
// ---------------------------------------------------------------------------
__global__ __launch_bounds__(512, 1) void fused_sde(
        const int* __restrict__ x, const float* __restrict__ cemb,
        const unsigned short* __restrict__ langb,
        const unsigned short* __restrict__ latbS,
        const unsigned short* __restrict__ latbT,
        float* __restrict__ out) {
    __shared__ unsigned short sLat[3][TILE_SH];   // 144 KB ring
    __shared__ unsigned short sP[2][TOKB * 40];   // 10 KB, row pitch 40
    __shared__ float sL[2][TOKB];

    const int tid  = threadIdx.x;
    const int w    = tid >> 6;
    const int lane = tid & 63;
    const int lr   = lane & 15;
    const int q    = lane >> 4;
    const int tt   = w & 3;          // S token tile
    const int lt   = w >> 2;         // S lat tile
    const int m0   = blockIdx.x * TOKB;

    uint4 qf[24];
    {
        const unsigned short* qr = langb + (m0 + tt * 16 + lr) * DIM;
        #pragma unroll
        for (int kf = 0; kf < 24; ++kf)
            qf[kf] = *(const uint4*)(qr + kf * 32 + q * 8);
    }

    f32x4 accO[4][6];
    #pragma unroll
    for (int mt = 0; mt < 4; ++mt)
        #pragma unroll
        for (int dt = 0; dt < 6; ++dt)
            accO[mt][dt] = (f32x4){0.f, 0.f, 0.f, 0.f};
    float lpart = 0.f;

    const int aBase = lt * 64 + lane;
    const int bBase = (w * 96 + lr) * 32 + q * 8;

    // Prologue: DMA tiles 0,1 -> bufs 0,1; wait tile 0 only (vmcnt(6)), barrier.
    #pragma unroll
    for (int i = 0; i < 6; ++i)
        async_cp16(latbS + ((size_t)i * 512 + tid) * 8,
                   &sLat[0][(i * 512 + (tid & ~63)) * 8]);
    __builtin_amdgcn_sched_barrier(0);
    #pragma unroll
    for (int i = 0; i < 6; ++i)
        async_cp16(latbS + (size_t)TILE_SH + ((size_t)i * 512 + tid) * 8,
                   &sLat[1][(i * 512 + (tid & ~63)) * 8]);
    __builtin_amdgcn_sched_barrier(0);
    asm volatile("s_waitcnt vmcnt(6)" ::: "memory");
    __builtin_amdgcn_sched_barrier(0);
    __builtin_amdgcn_s_barrier();
    __builtin_amdgcn_sched_barrier(0);

    uint4 bO[6];

    for (int s = 0; s < NSTEP; ++s) {
        const int c  = s & 1;
        const int rb = s % 3;

        // (1) bO(s-1) global->reg issue (oldest VMEM of this iter)
        if (s > 0) {
            const unsigned short* bt = latbT + (size_t)(s - 1) * TILE_SH;
            #pragma unroll
            for (int dt = 0; dt < 6; ++dt)
                bO[dt] = *(const uint4*)(bt + bBase + dt * 512);
        }
        __builtin_amdgcn_sched_barrier(0);
        // (2) DMA(s+2) -> ring buf (crosses this iter's barrier in flight)
        if (s + 2 < NSTEP) {
            const unsigned short* gs = latbS + (size_t)(s + 2) * TILE_SH;
            const int rn = (s + 2) % 3;
            #pragma unroll
            for (int i = 0; i < 6; ++i)
                async_cp16(gs + ((size_t)i * 512 + tid) * 8,
                           &sLat[rn][(i * 512 + (tid & ~63)) * 8]);
        }
        __builtin_amdgcn_sched_barrier(0);

        // (3) S(s): A from ring buf, Q in regs
        f32x4 sva = {0.f,0.f,0.f,0.f}, svb = {0.f,0.f,0.f,0.f};
        #pragma unroll
        for (int kp = 0; kp < 12; ++kp) {
            bf16x8 a0 = *(const bf16x8*)&sLat[rb][((2 * kp)     * 128 + aBase) * 8];
            bf16x8 a1 = *(const bf16x8*)&sLat[rb][((2 * kp + 1) * 128 + aBase) * 8];
            bf16x8 b0 = *(const bf16x8*)&qf[2 * kp];
            bf16x8 b1 = *(const bf16x8*)&qf[2 * kp + 1];
            sva = __builtin_amdgcn_mfma_f32_16x16x32_bf16(a0, b0, sva, 0, 0, 0);
            svb = __builtin_amdgcn_mfma_f32_16x16x32_bf16(a1, b1, svb, 0, 0, 0);
        }

        // (4) exp (no max-sub; |s| = O(1)), publish P(s)
        {
            const int lat0 = s * 32 + lt * 16 + q * 4;
            f32x4 sv = sva + svb;
            float e0 = (lat0     < KLAT) ? __expf(sv[0]) : 0.f;
            float e1 = (lat0 + 1 < KLAT) ? __expf(sv[1]) : 0.f;
            float e2 = (lat0 + 2 < KLAT) ? __expf(sv[2]) : 0.f;
            float e3 = (lat0 + 3 < KLAT) ? __expf(sv[3]) : 0.f;
            lpart += (e0 + e1) + (e2 + e3);
            unsigned int p01 = f2bf(e0) | (f2bf(e1) << 16);
            unsigned int p23 = f2bf(e2) | (f2bf(e3) << 16);
            *(uint2*)&sP[c][(tt * 16 + lr) * 40 + lt * 16 + q * 4] =
                make_uint2(p01, p23);
        }

        // (5) counted vmcnt: bO(s-1) ready; implies DMA(s+1) retired (older).
        if (s + 2 < NSTEP) {
            asm volatile("s_waitcnt vmcnt(6)" ::: "memory");
        } else {
            asm volatile("s_waitcnt vmcnt(0)" ::: "memory");
        }
        __builtin_amdgcn_sched_barrier(0);

        // (6) O(s-1): pure-register MFMA cluster
        if (s > 0) {
            bf16x8 pA[4];
            #pragma unroll
            for (int mt = 0; mt < 4; ++mt)
                pA[mt] = *(const bf16x8*)&sP[c ^ 1][(mt * 16 + lr) * 40 + q * 8];
            __builtin_amdgcn_s_setprio(1);
            #pragma unroll
            for (int dt = 0; dt < 6; ++dt) {
                bf16x8 b = *(const bf16x8*)&bO[dt];
                #pragma unroll
                for (int mt = 0; mt < 4; ++mt)
                    accO[mt][dt] = __builtin_amdgcn_mfma_f32_16x16x32_bf16(
                        pA[mt], b, accO[mt][dt], 0, 0, 0);
            }
            __builtin_amdgcn_s_setprio(0);
        }

        // (7) LDS-only barrier: sP(s) published, tile s+1 visible. DMA(s+2)
        //     stays in flight (no vmcnt drain here — the whole point).
        asm volatile("s_waitcnt lgkmcnt(0)" ::: "memory");
        __builtin_amdgcn_sched_barrier(0);
        __builtin_amdgcn_s_barrier();
        __builtin_amdgcn_sched_barrier(0);
    }

    // Tail: O(NSTEP-1). sP[(NSTEP-1)&1 = 0] published at last barrier.
    {
        const unsigned short* bt = latbT + (size_t)(NSTEP - 1) * TILE_SH;
        #pragma unroll
        for (int dt = 0; dt < 6; ++dt)
            bO[dt] = *(const uint4*)(bt + bBase + dt * 512);
        bf16x8 pA[4];
        #pragma unroll
        for (int mt = 0; mt < 4; ++mt)
            pA[mt] = *(const bf16x8*)&sP[0][(mt * 16 + lr) * 40 + q * 8];
        #pragma unroll
        for (int dt = 0; dt < 6; ++dt) {
            bf16x8 b = *(const bf16x8*)&bO[dt];
            #pragma unroll
            for (int mt = 0; mt < 4; ++mt)
                accO[mt][dt] = __builtin_amdgcn_mfma_f32_16x16x32_bf16(
                    pA[mt], b, accO[mt][dt], 0, 0, 0);
        }
    }

    // softmax denominator
    lpart += __shfl_xor(lpart, 16, 64);
    lpart += __shfl_xor(lpart, 32, 64);
    if (lane < 16) sL[lt][tt * 16 + lane] = lpart;
    __syncthreads();

    // epilogue: /l + lang + special-token override, fp32 out
    #pragma unroll
    for (int mt = 0; mt < 4; ++mt) {
        int tl0 = mt * 16 + q * 4;
        float linv[4]; int fid[4];
        #pragma unroll
        for (int r = 0; r < 4; ++r) {
            linv[r] = 1.0f / (sL[0][tl0 + r] + sL[1][tl0 + r]);
            fid[r]  = x[(m0 + tl0 + r) * 8];
        }
        #pragma unroll
        for (int dt = 0; dt < 6; ++dt) {
            int d = w * 96 + dt * 16 + lr;
            #pragma unroll
            for (int r = 0; r < 4; ++r) {
                int tok = m0 + tl0 + r;
                float v = accO[mt][dt][r] * linv[r] + bf2f(langb[tok * DIM + d]);
                if (fid[r] < 4) v = cemb[fid[r] * DIM + d];  // PAD/CLS/SEP/UNK
                out[tok * DIM + d] = v;
            }
        }
    }
}

// ---------------------------------------------------------------------------
extern "C" void kernel_launch(void* const* d_in, const int* in_sizes, int n_in,
                              void* d_out, int out_size, void* d_ws, size_t ws_size,
                              hipStream_t stream) {
    const int*   x      = (const int*)d_in[0];     // (16,1024,8) int
    const float* cemb   = (const float*)d_in[1];   // (30000,768) f32
    const float* latent = (const float*)d_in[2];   // (5000,768) f32
    float* out = (float*)d_out;                    // (16,1024,768) f32

    unsigned short* langb = (unsigned short*)d_ws;                  // 25.2 MB
    unsigned short* latbS = langb + (size_t)NTOK * DIM;             // 7.7 MB
    unsigned short* latbT = latbS + (size_t)NSTEP * TILE_SH;        // 7.7 MB

    int nS = NSTEP * 24 * 2 * 64;        // frag groups in latbS
    int nT = NSTEP * DIM * 4;            // 8-short groups in latbT
    cvt_latS<<<(nS + 255) / 256, 256, 0, stream>>>(latent, latbS);
    cvt_latT<<<(nT + 255) / 256, 256, 0, stream>>>(latent, latbT);
    build_lang<<<NTOK, 192, 0, stream>>>(x, cemb, langb);
    fused_sde<<<NTOK / TOKB, 512, 0, stream>>>(x, cemb, langb, latbS, latbT, out);
}